// Round 1
// baseline (60.607 us; speedup 1.0000x reference)
//
#include <hip/hip_runtime.h>

#define NBIN 35
#define BSZ 9
#define NOUT_PER_BIN 2001   // 9 + 45 + 165 + 495 + 1287

// Packed combination table: 5 nibbles per entry, lex order matching
// itertools.combinations_with_replacement. Sentinel index 9 -> v[9] == 1.0f.
struct PackTab { unsigned pk[NOUT_PER_BIN]; };

constexpr PackTab make_tab() {
    PackTab t{};
    int p = 0;
    constexpr unsigned S = 9;  // sentinel (multiplies by 1.0f)
    // order 1 (the bins themselves)
    for (unsigned a = 0; a < 9; ++a)
        t.pk[p++] = a | (S << 4) | (S << 8) | (S << 12) | (S << 16);
    // order 2
    for (unsigned a = 0; a < 9; ++a)
        for (unsigned b = a; b < 9; ++b)
            t.pk[p++] = a | (b << 4) | (S << 8) | (S << 12) | (S << 16);
    // order 3
    for (unsigned a = 0; a < 9; ++a)
        for (unsigned b = a; b < 9; ++b)
            for (unsigned c = b; c < 9; ++c)
                t.pk[p++] = a | (b << 4) | (c << 8) | (S << 12) | (S << 16);
    // order 4
    for (unsigned a = 0; a < 9; ++a)
        for (unsigned b = a; b < 9; ++b)
            for (unsigned c = b; c < 9; ++c)
                for (unsigned d = c; d < 9; ++d)
                    t.pk[p++] = a | (b << 4) | (c << 8) | (d << 12) | (S << 16);
    // order 5
    for (unsigned a = 0; a < 9; ++a)
        for (unsigned b = a; b < 9; ++b)
            for (unsigned c = b; c < 9; ++c)
                for (unsigned d = c; d < 9; ++d)
                    for (unsigned e = d; e < 9; ++e)
                        t.pk[p++] = a | (b << 4) | (c << 8) | (d << 12) | (e << 16);
    return t;
}

__constant__ PackTab g_tab = make_tab();

// One wave64 per (batch, bin) task. 4 waves per block.
__global__ __launch_bounds__(256) void poly_expand_kernel(
        const float* __restrict__ x, float* __restrict__ out, int ntask) {
    __shared__ float vs[4][12];   // 10 used per wave (9 vals + 1.0), padded
    const int wave = threadIdx.x >> 6;
    const int lane = threadIdx.x & 63;
    const int task = blockIdx.x * 4 + wave;
    const bool valid = task < ntask;

    if (valid && lane < 10) {
        vs[wave][lane] = (lane < 9) ? x[(size_t)task * BSZ + lane] : 1.0f;
    }
    __syncthreads();   // all threads reach this (no early return above)
    if (!valid) return;

    const float* v = vs[wave];
    const size_t base = (size_t)task * NOUT_PER_BIN;

    for (int j0 = 0; j0 < NOUT_PER_BIN; j0 += 64) {
        const int j = j0 + lane;
        if (j < NOUT_PER_BIN) {
            const unsigned pk = g_tab.pk[j];
            float p = v[pk & 15u];
            p *= v[(pk >> 4) & 15u];
            p *= v[(pk >> 8) & 15u];
            p *= v[(pk >> 12) & 15u];
            p *= v[(pk >> 16) & 15u];
            out[base + j] = p;
        }
    }
}

extern "C" void kernel_launch(void* const* d_in, const int* in_sizes, int n_in,
                              void* d_out, int out_size, void* d_ws, size_t ws_size,
                              hipStream_t stream) {
    const float* x = (const float*)d_in[0];
    float* out = (float*)d_out;
    const int B = in_sizes[0] / (NBIN * BSZ);
    const int ntask = B * NBIN;
    const int blocks = (ntask + 3) / 4;
    poly_expand_kernel<<<blocks, 256, 0, stream>>>(x, out, ntask);
}